// Round 9
// baseline (1916.348 us; speedup 1.0000x reference)
//
#include <hip/hip_runtime.h>
#include <cstdint>

#pragma clang fp contract(off)

#define N_PTS 8192
#define B_SZ  4
#define K_NN  20
#define O_CH  64
#define QW    64              // queries per block (= lanes; sorted-consecutive)
#define NWAVE 8
#define NTILE 128             // 64-point tiles per batch
#define CAPQ  88              // per-query survivor stack capacity
#define SPADQ 89              // stack row stride (u64)

typedef unsigned long long u64k;

// pd[n,m] = (-xx_n - inner) - xx_m, inner = -(2*dot) exact; fma(dot,2,-xxn)
// reproduces numpy's rounding exactly (2*dot exact, one rounding per add).
__device__ __forceinline__ float pd_np(float qx, float qy, float qz, float xxn,
                                       float cx, float cy, float cz, float xm) {
  float p0 = qx * cx;
  float p1 = qy * cy;
  float p2 = qz * cz;
  float dot = (p0 + p1) + p2;
  float t = __builtin_fmaf(dot, 2.0f, -xxn);
  return t - xm;
}

// values-only gated branchless sorted insert (ascending; keeps 20 largest)
__device__ __forceinline__ void insert20(float (&arr)[K_NN], float v) {
  float c = v;
#pragma unroll
  for (int u = K_NN - 1; u >= 0; --u) {
    float hi = fmaxf(arr[u], c);
    c = fminf(arr[u], c);
    arr[u] = hi;
  }
}

// packed-key sorted insert: key = (sortable_pd << 13) | (8191 - orig_j)
// u64 descending == (pd desc, j asc) == jax.lax.top_k set semantics.
__device__ __forceinline__ void insK(u64k (&a)[K_NN], u64k k) {
  u64k c = k;
#pragma unroll
  for (int u = K_NN - 1; u >= 0; --u) {
    bool g = a[u] > c;
    u64k hi = g ? a[u] : c;
    u64k lo = g ? c : a[u];
    a[u] = hi;
    c = lo;
  }
}

__device__ __forceinline__ unsigned sortable32(float v) {
  unsigned s = __float_as_uint(v);
  return s ^ ((unsigned)((int)s >> 31) | 0x80000000u);
}

__device__ __forceinline__ u64k packKey(float pd, int j) {
  return ((u64k)sortable32(pd) << 13) | (unsigned)(8191 - j);
}

__global__ __launch_bounds__(256, 2)
void pack_kernel(const float* __restrict__ x, float4* __restrict__ P) {
  int idx = blockIdx.x * 256 + threadIdx.x;   // b*N + n
  if (idx >= B_SZ * N_PTS) return;
  int b = idx >> 13;
  int n = idx & (N_PTS - 1);
  const float* xb = x + (size_t)b * 3 * N_PTS;
  float x0 = xb[n];
  float x1 = xb[n + N_PTS];
  float x2 = xb[n + 2 * N_PTS];
  float xxv = (x0 * x0 + x1 * x1) + x2 * x2;  // numpy order, no contraction
  P[idx] = make_float4(x0, x1, x2, xxv);
}

// One block per batch: bitonic sort 8192 keys (x-sortable<<32 | idx) in LDS.
__global__ __launch_bounds__(512)
void sort_kernel(const float4* __restrict__ P, float4* __restrict__ Ps,
                 int* __restrict__ SIdx) {
  extern __shared__ u64k A[];                 // 8192 u64 = 64 KB dynamic LDS
  const int b = blockIdx.x;
  const int t = threadIdx.x;
  const float4* __restrict__ Pb = P + (size_t)b * N_PTS;
  for (int i = t; i < N_PTS; i += 512)
    A[i] = ((u64k)sortable32(Pb[i].x) << 32) | (unsigned)i;
  __syncthreads();
  for (int k = 2; k <= N_PTS; k <<= 1) {
    for (int j = k >> 1; j > 0; j >>= 1) {
      for (int i = t; i < N_PTS; i += 512) {
        int ixj = i ^ j;
        if (ixj > i) {
          u64k a = A[i], c = A[ixj];
          bool up = ((i & k) == 0);
          if ((a > c) == up) { A[i] = c; A[ixj] = a; }
        }
      }
      __syncthreads();
    }
  }
  for (int i = t; i < N_PTS; i += 512) {
    int idx = (int)(A[i] & 0xFFFFFFFFu);
    Ps[(size_t)b * N_PTS + i] = Pb[idx];
    SIdx[(size_t)b * N_PTS + i] = idx;
  }
}

__global__ __launch_bounds__(512, 4)
void knn_edgeconv_kernel(const float4* __restrict__ Porig,
                         const float4* __restrict__ Ps,
                         const int* __restrict__ SIdx,
                         const float* __restrict__ W,
                         const float* __restrict__ bias,
                         float* __restrict__ out) {
  __shared__ u64k   stk[QW * SPADQ];      // 45.6 KB; warm scratch aliased below
  __shared__ float4 tbuf[NWAVE][64];      // per-wave staged candidate tile
  __shared__ int    tidx[NWAVE][64];
  __shared__ float  tau_l[QW];
  __shared__ int    cnt_l[QW];
  __shared__ int    list_l[QW][21];

  const int t   = threadIdx.x;
  const int ql  = t & 63;
  const int s   = t >> 6;
  const int wb  = blockIdx.x;             // 0..511
  const int b   = wb >> 7;
  const int blk = wb & 127;               // sorted-query block

  const float4* __restrict__ Psb = Ps + (size_t)b * N_PTS;
  const int*    __restrict__ SIb = SIdx + (size_t)b * N_PTS;
  const float4* __restrict__ Pob = Porig + (size_t)b * N_PTS;

  const int sp = (blk << 6) + ql;         // sorted position of my query
  const float4 qc = Psb[sp];
  const float qx = qc.x, qy = qc.y, qz = qc.z, xxn = qc.w;
  const int oq = SIb[sp];                 // original query index

  const int sw = __builtin_amdgcn_readfirstlane(s);
  const int myq = (sw << 3) + ql;         // drain-role query (lanes ql<8)

  // ---- Warm: wave w stages+scans tile wbase+w (512 spatially-near cands) ----
  const int wbase = min(max(blk - 3, 0), NTILE - NWAVE);
  float arrv[K_NN];
#pragma unroll
  for (int i = 0; i < K_NN; ++i) arrv[i] = -__builtin_inff();
  {
    const int tw = wbase + sw;
    tbuf[sw][ql] = Psb[(tw << 6) + ql];
    asm volatile("s_waitcnt lgkmcnt(0)" ::: "memory");
    __builtin_amdgcn_sched_barrier(0);
#pragma unroll 4
    for (int jj = 0; jj < 64; ++jj) {
      float4 cd = tbuf[sw][jj];
      float pdv = pd_np(qx, qy, qz, xxn, cd.x, cd.y, cd.z, cd.w);
      if (pdv > arrv[0]) insert20(arrv, pdv);
    }
    float* WV = (float*)stk;
#pragma unroll
    for (int i = 0; i < K_NN; ++i) WV[((sw << 6) + ql) * 21 + i] = arrv[i];
  }
  __syncthreads();

  // ---- Merge (every wave, redundant): tau0 = exact 20th of 512 warm cands ----
  {
    const float* WV = (const float*)stk;
    for (int p = 0; p < NWAVE; ++p) {
      if (p == sw) continue;
      const float* pv = WV + ((p << 6) + ql) * 21;
      for (int i = 0; i < K_NN; ++i) {
        float v = pv[i];
        if (v > arrv[0]) insert20(arrv, v);
      }
    }
  }
  const float tau0 = arrv[0];             // certified: tau0 <= final 20th pd
  if (s == 0) {
    tau_l[ql] = tau0;
    cnt_l[ql] = 0;
  }
  __syncthreads();                        // WV dead; stk becomes stacks

  // ---- Alive tile range from radius r = sqrt(-tau0) (conservative margin) ----
  float r = sqrtf(fmaxf(-tau0, 0.0f));
  r = __builtin_fmaf(r, 1.0001f, 1e-6f);
  float xlo = qx - r, xhi = qx + r;
#pragma unroll
  for (int m = 1; m < 64; m <<= 1) {
    xlo = fminf(xlo, __shfl_xor(xlo, m, 64));
    xhi = fmaxf(xhi, __shfl_xor(xhi, m, 64));
  }
  // lane l tests tiles l and 64+l (sorted => alive set is contiguous)
  float t0a = Psb[(ql << 6)].x,        t0b = Psb[(ql << 6) + 63].x;
  float t1a = Psb[((64 + ql) << 6)].x, t1b = Psb[((64 + ql) << 6) + 63].x;
  u64k m0 = __ballot((t0b >= xlo) && (t0a <= xhi));
  u64k m1 = __ballot((t1b >= xlo) && (t1a <= xhi));
  const int tL = m0 ? (int)__builtin_ctzll(m0) : 64 + (int)__builtin_ctzll(m1);
  const int tR = m1 ? 127 - (int)__builtin_clzll(m1) : 63 - (int)__builtin_clzll(m0);

  // ---- Pruned scan: wave w takes tiles tL+w, tL+w+8, ... (stage via LDS) ----
  for (int tt = tL + sw; tt <= tR; tt += NWAVE) {
    tbuf[sw][ql] = Psb[(tt << 6) + ql];
    tidx[sw][ql] = SIb[(tt << 6) + ql];
    asm volatile("s_waitcnt lgkmcnt(0)" ::: "memory");
    __builtin_amdgcn_sched_barrier(0);
#pragma unroll 8
    for (int jj = 0; jj < 64; ++jj) {
      float4 cd = tbuf[sw][jj];
      float pdv = pd_np(qx, qy, qz, xxn, cd.x, cd.y, cd.z, cd.w);
      if (pdv >= tau0) {                  // >= : keep boundary ties
        int oj = tidx[sw][jj];
        int slot = atomicAdd(&cnt_l[ql], 1);
        if (slot < CAPQ) stk[ql * SPADQ + slot] = packKey(pdv, oj);
      }
    }
  }
  __syncthreads();

  // ---- Drain (64-way lane-parallel) + publish ----
  if (ql < 8) {
    u64k karr[K_NN];
#pragma unroll
    for (int i = 0; i < K_NN; ++i) karr[i] = 0ULL;
    const int pc = cnt_l[myq];
    if (pc <= CAPQ) {
      const u64k* ps = &stk[myq * SPADQ];
      for (int i = 0; i < pc; ++i) {
        u64k k = ps[i];
        if (k > karr[0]) insK(karr, k);
      }
    } else {                              // rare: exact in-range rescan
      const float tauc = tau_l[myq];
      float4 mq = Psb[(blk << 6) + myq];
      for (int sp2 = (tL << 6); sp2 < ((tR + 1) << 6); ++sp2) {
        float4 cd = Psb[sp2];
        float pdv = pd_np(mq.x, mq.y, mq.z, mq.w, cd.x, cd.y, cd.z, cd.w);
        if (pdv >= tauc) {
          u64k k = packKey(pdv, SIb[sp2]);
          if (k > karr[0]) insK(karr, k);
        }
      }
    }
#pragma unroll
    for (int i = 0; i < K_NN; ++i)
      list_l[myq][i] = 8191 - (int)(karr[i] & 8191ULL);
  }
  __syncthreads();

  // ---- EdgeConv: max_j( W[:,0:3]·(x_m - x_n) ) + center term, leaky relu ----
  float acc[8];
#pragma unroll
  for (int oi = 0; oi < 8; ++oi) acc[oi] = -__builtin_inff();
  const int o0 = s * 8;
  const float* __restrict__ Wp = W + o0 * 6;

  for (int nb = 0; nb < K_NN; ++nb) {
    int m = list_l[ql][nb] & (N_PTS - 1);   // mask: memory-safety belt
    float4 cm = Pob[m];
    float dx = cm.x - qx;
    float dy = cm.y - qy;
    float dz = cm.z - qz;
#pragma unroll
    for (int oi = 0; oi < 8; ++oi) {
      float h = __builtin_fmaf(dz, Wp[oi * 6 + 2],
                __builtin_fmaf(dy, Wp[oi * 6 + 1], dx * Wp[oi * 6 + 0]));
      acc[oi] = fmaxf(acc[oi], h);
    }
  }

#pragma unroll
  for (int oi = 0; oi < 8; ++oi) {
    int o = o0 + oi;
    float base = __builtin_fmaf(qz, Wp[oi * 6 + 5],
                 __builtin_fmaf(qy, Wp[oi * 6 + 4], qx * Wp[oi * 6 + 3])) + bias[o];
    float v = acc[oi] + base;
    v = fmaxf(v, 0.2f * v);                 // leaky_relu (monotone, commutes with max)
    out[((size_t)(b * O_CH + o) << 13) + oq] = v;
  }
}

extern "C" void kernel_launch(void* const* d_in, const int* in_sizes, int n_in,
                              void* d_out, int out_size, void* d_ws, size_t ws_size,
                              hipStream_t stream) {
  const float* x    = (const float*)d_in[0];
  const float* W    = (const float*)d_in[1];
  const float* bias = (const float*)d_in[2];
  char* ws = (char*)d_ws;
  float4* P    = (float4*)ws;                       // 512 KB (orig order)
  float4* Ps   = (float4*)(ws + 512 * 1024);        // 512 KB (x-sorted)
  int*    SIdx = (int*)(ws + 1024 * 1024);          // 128 KB (sorted->orig)
  float* out = (float*)d_out;

  pack_kernel<<<dim3((B_SZ * N_PTS + 255) / 256), dim3(256), 0, stream>>>(x, P);
  sort_kernel<<<dim3(B_SZ), dim3(512), N_PTS * sizeof(u64k), stream>>>(P, Ps, SIdx);
  knn_edgeconv_kernel<<<dim3(B_SZ * (N_PTS / QW)), dim3(512), 0, stream>>>(
      P, Ps, SIdx, W, bias, out);
}

// Round 10
// 865.184 us; speedup vs baseline: 2.2150x; 2.2150x over previous
//
#include <hip/hip_runtime.h>
#include <cstdint>

#pragma clang fp contract(off)

#define N_PTS 8192
#define B_SZ  4
#define K_NN  20
#define O_CH  64
#define QW    64              // queries per block (= lanes per wave)
#define SSUB  16              // candidate subsets per query == waves per block
#define NTHR  (QW * SSUB)     // 1024 threads
#define SUBL  (N_PTS / SSUB)  // 512
#define WARM  64              // warm-up candidates per thread (values-only)
#define CAP   7               // survivor stack capacity per thread per chunk
#define SPAD  8               // stack row stride (u64)
#define NCH   4               // chunks per subset

typedef unsigned long long u64k;

// pd = -xx_n - (-2*dot) - xx_m with numpy rounding order.
// fma(dot,2,-xxn): 2*dot is exact => identical bits to round(2dot - xxn).
__device__ __forceinline__ float pd_np(float qx, float qy, float qz, float xxn,
                                       float cx, float cy, float cz, float xm) {
  float p0 = qx * cx;
  float p1 = qy * cy;
  float p2 = qz * cz;
  float dot = (p0 + p1) + p2;
  float t = __builtin_fmaf(dot, 2.0f, -xxn);
  return t - xm;
}

// values-only gated branchless sorted insert (ascending; keeps 20 largest)
__device__ __forceinline__ void insert20(float (&arr)[K_NN], float v) {
  float c = v;
#pragma unroll
  for (int u = K_NN - 1; u >= 0; --u) {
    float hi = fmaxf(arr[u], c);
    c = fminf(arr[u], c);
    arr[u] = hi;
  }
}

// packed-key sorted insert: key = (sortable_pd << 13) | (8191 - j)
// u64 descending == (pd desc, j asc) == jax.lax.top_k order (set semantics).
__device__ __forceinline__ void insK(u64k (&a)[K_NN], u64k k) {
  u64k c = k;
#pragma unroll
  for (int u = K_NN - 1; u >= 0; --u) {
    bool g = a[u] > c;
    u64k hi = g ? a[u] : c;
    u64k lo = g ? c : a[u];
    a[u] = hi;
    c = lo;
  }
}

__device__ __forceinline__ unsigned sortable32(float pd) {
  unsigned s = __float_as_uint(pd);
  return s ^ ((unsigned)((int)s >> 31) | 0x80000000u);
}

__device__ __forceinline__ u64k packKey(float pd, int j) {
  return ((u64k)sortable32(pd) << 13) | (unsigned)(8191 - j);
}

__device__ __forceinline__ float keyPd(u64k k) {
  unsigned sp = (unsigned)(k >> 13);
  unsigned s = (sp & 0x80000000u) ? (sp & 0x7FFFFFFFu) : ~sp;
  return __uint_as_float(s);
}

__global__ __launch_bounds__(256, 2)
void pack_kernel(const float* __restrict__ x, float4* __restrict__ P) {
  int idx = blockIdx.x * 256 + threadIdx.x;   // b*N + n
  if (idx >= B_SZ * N_PTS) return;
  int b = idx >> 13;
  int n = idx & (N_PTS - 1);
  const float* xb = x + (size_t)b * 3 * N_PTS;
  float x0 = xb[n];
  float x1 = xb[n + N_PTS];
  float x2 = xb[n + 2 * N_PTS];
  float xxv = (x0 * x0 + x1 * x1) + x2 * x2;  // numpy order, no contraction
  P[idx] = make_float4(x0, x1, x2, xxv);
}

__global__ __launch_bounds__(NTHR, 8)
void knn_edgeconv_kernel(const float4* __restrict__ P,
                         const float* __restrict__ W,
                         const float* __restrict__ bias,
                         float* __restrict__ out) {
  __shared__ u64k  stk[NTHR * SPAD];  // 64 KB; warm scratch aliased (2 passes)
  __shared__ int   cnt_l[NTHR];
  __shared__ short of_l[NTHR];
  __shared__ float tau_l[QW];
  __shared__ int   list_l[QW][21];

  const int t  = threadIdx.x;
  const int ql = t & 63;
  const int s  = t >> 6;              // wave id == subset 0..15
  const int wb = blockIdx.x;          // 0..511
  const int b  = wb >> 7;
  const int n0 = (wb & 127) << 6;
  const int q  = n0 + ql;

  const float4* __restrict__ Pb = P + (size_t)b * N_PTS;

  const float4 qc = Pb[q];
  const float qx = qc.x, qy = qc.y, qz = qc.z, xxn = qc.w;

  const int sw   = __builtin_amdgcn_readfirstlane(s);
  const int j0   = sw * SUBL;
  const int CB[NCH + 1] = {0, 64, 160, 320, 512};

  // ---- Warm-up: values-only top-20 of first WARM own candidates ----
  float arrv[K_NN];
#pragma unroll
  for (int i = 0; i < K_NN; ++i) arrv[i] = -__builtin_inff();
#pragma unroll 4
  for (int jj = 0; jj < WARM; ++jj) {
    int j = j0 + jj;
    float4 cd = Pb[j];
    float pdv = pd_np(qx, qy, qz, xxn, cd.x, cd.y, cd.z, cd.w);
    if (pdv > arrv[0]) insert20(arrv, pdv);
  }

  // ---- Merge 16 warm lists -> tau0 (exact 20th of 1024-sample), 2 passes ----
  // Pass A: waves 0-7 publish; wave-0 lanes fold 8 lists into registers.
  float mreg[K_NN];
#pragma unroll
  for (int i = 0; i < K_NN; ++i) mreg[i] = -__builtin_inff();
  {
    float* WV = (float*)stk;          // 512*21*4 = 43 KB <= 64 KB alias
    if (sw < 8) {
#pragma unroll
      for (int i = 0; i < K_NN; ++i) WV[((sw << 6) + ql) * 21 + i] = arrv[i];
    }
    __syncthreads();
    if (t < QW) {
      for (int p = 0; p < 8; ++p) {
        const float* pv = WV + ((p << 6) + t) * 21;
        for (int i = 0; i < K_NN; ++i) {
          float v = pv[i];
          if (v > mreg[0]) insert20(mreg, v);
        }
      }
    }
    __syncthreads();
    // Pass B: waves 8-15 publish; wave-0 lanes fold the rest.
    if (sw >= 8) {
#pragma unroll
      for (int i = 0; i < K_NN; ++i) WV[(((sw - 8) << 6) + ql) * 21 + i] = arrv[i];
    }
    __syncthreads();
    if (t < QW) {
      for (int p = 0; p < 8; ++p) {
        const float* pv = WV + ((p << 6) + t) * 21;
        for (int i = 0; i < K_NN; ++i) {
          float v = pv[i];
          if (v > mreg[0]) insert20(mreg, v);
        }
      }
      tau_l[t] = mreg[0];
    }
  }
  __syncthreads();                    // WV dead; stk becomes per-thread stacks

  // ---- Chunked filtered scan; wave-0 lanes drain after each chunk ----
  u64k karr[K_NN];
#pragma unroll
  for (int i = 0; i < K_NN; ++i) karr[i] = 0ULL;

  for (int c = 0; c < NCH; ++c) {
    {
      const float tau = tau_l[ql];
      int cnt = 0, ofj = -1;
      const int jb = j0 + CB[c];
      const int je = j0 + CB[c + 1];
      u64k* my = stk + (size_t)t * SPAD;
#pragma unroll 4
      for (int j = jb; j < je; ++j) {
        float4 cd = Pb[j];
        float pdv = pd_np(qx, qy, qz, xxn, cd.x, cd.y, cd.z, cd.w);
        if (pdv >= tau) {               // >= : keep boundary ties
          if (cnt < CAP) { my[cnt] = packKey(pdv, j); ++cnt; }
          else if (ofj < 0) ofj = j;    // deterministic overflow fallback
        }
      }
      cnt_l[t] = cnt;
      of_l[t]  = (short)(ofj < 0 ? -1 : (ofj - j0));
    }
    __syncthreads();

    if (t < QW) {                       // drain: lane t owns query t
      const float tauc = tau_l[t];
      for (int p = 0; p < SSUB; ++p) {
        const int pt = (p << 6) + t;
        const int pc = cnt_l[pt];
        const u64k* ps = stk + (size_t)pt * SPAD;
        for (int i = 0; i < pc; ++i) {
          u64k k = ps[i];
          if (k > karr[0]) insK(karr, k);
        }
      }
      for (int p = 0; p < SSUB; ++p) {  // rare: exact overflow-tail rescan
        const int pt = (p << 6) + t;
        int oj = of_l[pt];
        if (oj >= 0) {
          const int pb = p * SUBL;
          for (int j = pb + oj; j < pb + CB[c + 1]; ++j) {
            float4 cd = Pb[j];
            float pdv = pd_np(qx, qy, qz, xxn, cd.x, cd.y, cd.z, cd.w);
            if (pdv >= tauc) {
              u64k k = packKey(pdv, j);
              if (k > karr[0]) insK(karr, k);
            }
          }
        }
      }
      float t20 = keyPd(karr[0]);       // NaN while karr not full -> fmaxf keeps old
      tau_l[t] = fmaxf(tauc, t20);
    }
    __syncthreads();
  }

  // ---- Publish final neighbor indices ----
  if (t < QW) {
#pragma unroll
    for (int i = 0; i < K_NN; ++i)
      list_l[t][i] = 8191 - (int)(karr[i] & 8191ULL);
  }
  __syncthreads();

  // ---- EdgeConv: max_j( W[:,0:3]·(x_m - x_n) ) + center term, leaky relu ----
  float acc[4];
#pragma unroll
  for (int oi = 0; oi < 4; ++oi) acc[oi] = -__builtin_inff();
  const int o0 = s * 4;
  const float* __restrict__ Wp = W + o0 * 6;

  for (int nb = 0; nb < K_NN; ++nb) {
    int m = list_l[ql][nb] & (N_PTS - 1);   // mask: memory-safety belt
    float4 cm = Pb[m];
    float dx = cm.x - qx;
    float dy = cm.y - qy;
    float dz = cm.z - qz;
#pragma unroll
    for (int oi = 0; oi < 4; ++oi) {
      float h = __builtin_fmaf(dz, Wp[oi * 6 + 2],
                __builtin_fmaf(dy, Wp[oi * 6 + 1], dx * Wp[oi * 6 + 0]));
      acc[oi] = fmaxf(acc[oi], h);
    }
  }

#pragma unroll
  for (int oi = 0; oi < 4; ++oi) {
    int o = o0 + oi;
    float base = __builtin_fmaf(qz, Wp[oi * 6 + 5],
                 __builtin_fmaf(qy, Wp[oi * 6 + 4], qx * Wp[oi * 6 + 3])) + bias[o];
    float v = acc[oi] + base;
    v = fmaxf(v, 0.2f * v);                 // leaky_relu (monotone, commutes with max)
    out[((size_t)(b * O_CH + o) << 13) + q] = v;
  }
}

extern "C" void kernel_launch(void* const* d_in, const int* in_sizes, int n_in,
                              void* d_out, int out_size, void* d_ws, size_t ws_size,
                              hipStream_t stream) {
  const float* x    = (const float*)d_in[0];
  const float* W    = (const float*)d_in[1];
  const float* bias = (const float*)d_in[2];
  float4* P  = (float4*)d_ws;               // B*N float4 = 512 KB
  float* out = (float*)d_out;

  pack_kernel<<<dim3((B_SZ * N_PTS + 255) / 256), dim3(256), 0, stream>>>(x, P);
  knn_edgeconv_kernel<<<dim3(B_SZ * (N_PTS / QW)), dim3(NTHR), 0, stream>>>(P, W, bias, out);
}